// Round 1
// baseline (1101.099 us; speedup 1.0000x reference)
//
#include <hip/hip_runtime.h>
#include <math.h>

#define DEVINL __device__ __forceinline__

DEVINL float gelu_f(float v) { return 0.5f * v * (1.0f + erff(v * 0.7071067811865475f)); }
DEVINL float lrelu_f(float v) { return v > 0.0f ? v : 0.2f * v; }

// ---------------- style: style = gelu(z_g@W_s1+b_s1)@W_s2 + b_s2 ----------------
__global__ void style_k(const float* __restrict__ zg, const float* __restrict__ W1,
                        const float* __restrict__ b1, const float* __restrict__ W2,
                        const float* __restrict__ b2, float* __restrict__ style) {
    __shared__ float s1[128];
    int j = threadIdx.x;
    float a = b1[j];
    for (int k = 0; k < 256; k++) a = fmaf(zg[k], W1[k * 128 + j], a);
    s1[j] = gelu_f(a);
    __syncthreads();
    float o = b2[j];
    for (int k = 0; k < 128; k++) o = fmaf(s1[k], W2[k * 128 + j], o);
    style[j] = o;
}

// ---------------- node-embed layer 1: h1 = gelu(tv@W_ne1 + b_ne1) ----------------
__global__ void ne1_k(const float* __restrict__ tv, const float* __restrict__ W,
                      const float* __restrict__ b, float* __restrict__ h1, int Nn) {
    int idx = blockIdx.x * blockDim.x + threadIdx.x;
    if (idx >= Nn * 128) return;
    int n = idx >> 7, c = idx & 127;
    float o = fmaf(tv[n * 3 + 0], W[c],
              fmaf(tv[n * 3 + 1], W[128 + c],
              fmaf(tv[n * 3 + 2], W[256 + c], b[c])));
    h1[idx] = gelu_f(o);
}

// ---------------- generic linear: out[n,j] = act(in[n,:]@W + b[j]) (+style) ------
// K fixed at 128. OUT in {64,128,256}. LDS-staged input rows; wave-uniform
// broadcast LDS reads (no bank conflicts); coalesced W reads (L2-resident).
template <int OUT, bool GELUACT, bool STYLE>
__global__ __launch_bounds__(256) void linear_k(const float* __restrict__ in,
                                                const float* __restrict__ W,
                                                const float* __restrict__ bias,
                                                const float* __restrict__ style,
                                                float* __restrict__ out, int Nn) {
    constexpr int K = 128;
    constexpr int JW = OUT;          // 64,128,256
    constexpr int G = 256 / JW;      // column groups per block
    constexpr int TM = 8;            // rows per group
    constexpr int ROWS = TM * G;
    __shared__ float lds[ROWS][K];
    int t = threadIdx.x;
    int j = t % JW, g = t / JW;
    int row0 = blockIdx.x * ROWS;

    constexpr int F4 = ROWS * K / 4;
    for (int i = t; i < F4; i += 256) {
        int r = i >> 5;            // 32 float4 per row
        int kk = (i & 31) << 2;
        float4 v = make_float4(0.f, 0.f, 0.f, 0.f);
        if (row0 + r < Nn) v = *reinterpret_cast<const float4*>(&in[(size_t)(row0 + r) * K + kk]);
        *reinterpret_cast<float4*>(&lds[r][kk]) = v;
    }
    __syncthreads();

    float acc[TM];
#pragma unroll
    for (int nn = 0; nn < TM; nn++) acc[nn] = 0.f;

    for (int k = 0; k < K; k += 4) {
        float w0 = W[(k + 0) * OUT + j];
        float w1 = W[(k + 1) * OUT + j];
        float w2 = W[(k + 2) * OUT + j];
        float w3 = W[(k + 3) * OUT + j];
#pragma unroll
        for (int nn = 0; nn < TM; nn++) {
            float4 a = *reinterpret_cast<const float4*>(&lds[g * TM + nn][k]);
            acc[nn] = fmaf(a.x, w0, acc[nn]);
            acc[nn] = fmaf(a.y, w1, acc[nn]);
            acc[nn] = fmaf(a.z, w2, acc[nn]);
            acc[nn] = fmaf(a.w, w3, acc[nn]);
        }
    }
    float bj = bias[j];
    float st = STYLE ? style[j] : 0.f;
#pragma unroll
    for (int nn = 0; nn < TM; nn++) {
        int r = row0 + g * TM + nn;
        if (r < Nn) {
            float o = acc[nn] + bj;
            if (GELUACT) o = gelu_f(o);
            if (STYLE) o += st;
            out[(size_t)r * OUT + j] = o;
        }
    }
}

// ---------------- CSR build (by destination), self-loops appended ----------------
__global__ void count_k(const int* __restrict__ dst, int* __restrict__ counts, int E, int EP) {
    int e = blockIdx.x * blockDim.x + threadIdx.x;
    if (e >= EP) return;
    int d = (e < E) ? dst[e] : (e - E);
    atomicAdd(&counts[d], 1);
}

__global__ void scan_k(const int* __restrict__ counts, int* __restrict__ rowptr, int Nn, int total) {
    __shared__ int part[1024];
    int tid = threadIdx.x;
    int chunk = (Nn + 1023) >> 10;
    int s = tid * chunk, e = min(s + chunk, Nn);
    int loc = 0;
    for (int i = s; i < e; i++) loc += counts[i];
    part[tid] = loc;
    __syncthreads();
    for (int off = 1; off < 1024; off <<= 1) {
        int v = (tid >= off) ? part[tid - off] : 0;
        __syncthreads();
        part[tid] += v;
        __syncthreads();
    }
    int run = part[tid] - loc;  // exclusive
    for (int i = s; i < e; i++) { rowptr[i] = run; run += counts[i]; }
    if (e == Nn) rowptr[Nn] = total;
}

__global__ void fill_k(const int* __restrict__ src, const int* __restrict__ dst,
                       const int* __restrict__ rowptr, int* __restrict__ fillc,
                       int* __restrict__ col, int E, int EP) {
    int e = blockIdx.x * blockDim.x + threadIdx.x;
    if (e >= EP) return;
    int d = (e < E) ? dst[e] : (e - E);
    int s = (e < E) ? src[e] : (e - E);
    int pos = atomicAdd(&fillc[d], 1);
    col[rowptr[d] + pos] = s;
}

// ---------------- GATv2 gather: online softmax per (node, head) ------------------
// One wave per head; lane l owns channels l and l+64. xl[src] row is read once
// and kept in registers for both the logit dot and the weighted accumulation.
template <int H>
__global__ void gat_gather_k(const float* __restrict__ xl, const float* __restrict__ xr,
                             const float* __restrict__ att, const float* __restrict__ bo,
                             const int* __restrict__ rowptr, const int* __restrict__ col,
                             float* __restrict__ y, int Nn) {
    int n = blockIdx.x;
    int h = threadIdx.x >> 6;
    int lane = threadIdx.x & 63;
    constexpr int HC = H * 128;

    float xr0 = xr[(size_t)n * HC + h * 128 + lane];
    float xr1 = xr[(size_t)n * HC + h * 128 + 64 + lane];
    float a0 = att[h * 128 + lane];
    float a1 = att[h * 128 + 64 + lane];

    float m = -1e30f, den = 0.f, acc0 = 0.f, acc1 = 0.f;
    int beg = rowptr[n], endp = rowptr[n + 1];
    for (int k = beg; k < endp; k++) {
        int s = col[k];
        float v0 = xl[(size_t)s * HC + h * 128 + lane];
        float v1 = xl[(size_t)s * HC + h * 128 + 64 + lane];
        float e0 = lrelu_f(v0 + xr0);
        float e1 = lrelu_f(v1 + xr1);
        float p = fmaf(e0, a0, e1 * a1);
#pragma unroll
        for (int off = 32; off > 0; off >>= 1) p += __shfl_xor(p, off, 64);
        float nm = fmaxf(m, p);
        float sc = __expf(m - nm);
        float pe = __expf(p - nm);
        den = fmaf(den, sc, pe);
        acc0 = fmaf(acc0, sc, pe * v0);
        acc1 = fmaf(acc1, sc, pe * v1);
        m = nm;
    }
    float inv = 1.0f / (den + 1e-16f);
    acc0 *= inv; acc1 *= inv;

    if constexpr (H == 1) {
        y[(size_t)n * 128 + lane] = acc0 + bo[lane];
        y[(size_t)n * 128 + 64 + lane] = acc1 + bo[64 + lane];
    } else {
        __shared__ float sh[H][128];
        sh[h][lane] = acc0;
        sh[h][64 + lane] = acc1;
        __syncthreads();
        if (threadIdx.x < 128) {
            float v = 0.f;
#pragma unroll
            for (int hh = 0; hh < H; hh++) v += sh[hh][threadIdx.x];
            y[(size_t)n * 128 + threadIdx.x] = v * (1.0f / H) + bo[threadIdx.x];
        }
    }
}

// ---------------- GraphNorm stats: per-channel sum & sumsq -----------------------
__global__ void gn_stats_k(const float* __restrict__ y, float* __restrict__ stats, int Nn) {
    int c = threadIdx.x;  // 128 threads
    int per = (Nn + gridDim.x - 1) / gridDim.x;
    int n0 = blockIdx.x * per, n1 = min(n0 + per, Nn);
    float s = 0.f, s2 = 0.f;
    for (int n = n0; n < n1; n++) {
        float v = y[(size_t)n * 128 + c];
        s += v;
        s2 = fmaf(v, v, s2);
    }
    atomicAdd(&stats[c], s);
    atomicAdd(&stats[128 + c], s2);
}

// ---------------- GraphNorm apply + GELU -----------------------------------------
__global__ void gn_apply_k(const float* __restrict__ y, const float* __restrict__ stats,
                           const float* __restrict__ w, const float* __restrict__ b,
                           const float* __restrict__ ms, float* __restrict__ xo, int Nn) {
    int i4 = blockIdx.x * blockDim.x + threadIdx.x;
    if (i4 >= Nn * 32) return;
    float4 v = reinterpret_cast<const float4*>(y)[i4];
    int c0 = (i4 & 31) * 4;
    float o[4] = {v.x, v.y, v.z, v.w};
    float invN = 1.0f / (float)Nn;
#pragma unroll
    for (int jj = 0; jj < 4; jj++) {
        int c = c0 + jj;
        float mu = stats[c] * invN;
        float ex2 = stats[128 + c] * invN;
        float msv = ms[c];
        float var = ex2 - 2.f * msv * mu * mu + msv * msv * mu * mu;
        float ov = o[jj] - msv * mu;
        float r = rsqrtf(var + 1e-5f);
        o[jj] = gelu_f(fmaf(w[c], ov * r, b[c]));
    }
    float4 res = make_float4(o[0], o[1], o[2], o[3]);
    reinterpret_cast<float4*>(xo)[i4] = res;
}

// ---------------- final head: out = h@W_h2 + b_h2 (OUT=3) ------------------------
__global__ void head2_k(const float* __restrict__ h, const float* __restrict__ W,
                        const float* __restrict__ b, float* __restrict__ out, int Nn) {
    __shared__ float w[192];
    __shared__ float bb[3];
    int t = threadIdx.x;
    if (t < 192) w[t] = W[t];
    if (t < 3) bb[t] = b[t];
    __syncthreads();
    int n = blockIdx.x * blockDim.x + t;
    if (n >= Nn) return;
    float a0 = bb[0], a1 = bb[1], a2 = bb[2];
    const float4* h4 = reinterpret_cast<const float4*>(h + (size_t)n * 64);
    for (int k4 = 0; k4 < 16; k4++) {
        float4 v = h4[k4];
        int k = k4 * 4;
        a0 = fmaf(v.x, w[(k + 0) * 3 + 0], a0); a1 = fmaf(v.x, w[(k + 0) * 3 + 1], a1); a2 = fmaf(v.x, w[(k + 0) * 3 + 2], a2);
        a0 = fmaf(v.y, w[(k + 1) * 3 + 0], a0); a1 = fmaf(v.y, w[(k + 1) * 3 + 1], a1); a2 = fmaf(v.y, w[(k + 1) * 3 + 2], a2);
        a0 = fmaf(v.z, w[(k + 2) * 3 + 0], a0); a1 = fmaf(v.z, w[(k + 2) * 3 + 1], a1); a2 = fmaf(v.z, w[(k + 2) * 3 + 2], a2);
        a0 = fmaf(v.w, w[(k + 3) * 3 + 0], a0); a1 = fmaf(v.w, w[(k + 3) * 3 + 1], a1); a2 = fmaf(v.w, w[(k + 3) * 3 + 2], a2);
    }
    out[n * 3 + 0] = a0;
    out[n * 3 + 1] = a1;
    out[n * 3 + 2] = a2;
}

extern "C" void kernel_launch(void* const* d_in, const int* in_sizes, int n_in,
                              void* d_out, int out_size, void* d_ws, size_t ws_size,
                              hipStream_t stream) {
    const float* zg = (const float*)d_in[0];
    const int* ei = (const int*)d_in[1];
    const float* tv = (const float*)d_in[2];
    const float* W_ne1 = (const float*)d_in[3];
    const float* b_ne1 = (const float*)d_in[4];
    const float* W_ne2 = (const float*)d_in[5];
    const float* b_ne2 = (const float*)d_in[6];
    const float* W_s1 = (const float*)d_in[7];
    const float* b_s1 = (const float*)d_in[8];
    const float* W_s2 = (const float*)d_in[9];
    const float* b_s2 = (const float*)d_in[10];
    const float *Wl[3], *bl[3], *Wr[3], *br[3], *attp[3], *bop[3], *gnw[3], *gnb[3], *gnms[3];
    for (int L = 0; L < 3; L++) {
        int base = 11 + L * 9;
        Wl[L] = (const float*)d_in[base + 0];
        bl[L] = (const float*)d_in[base + 1];
        Wr[L] = (const float*)d_in[base + 2];
        br[L] = (const float*)d_in[base + 3];
        attp[L] = (const float*)d_in[base + 4];
        bop[L] = (const float*)d_in[base + 5];
        gnw[L] = (const float*)d_in[base + 6];
        gnb[L] = (const float*)d_in[base + 7];
        gnms[L] = (const float*)d_in[base + 8];
    }
    const float* W_h1 = (const float*)d_in[38];
    const float* b_h1 = (const float*)d_in[39];
    const float* W_h2 = (const float*)d_in[40];
    const float* b_h2 = (const float*)d_in[41];

    int E = in_sizes[1] / 2;
    int N = in_sizes[2] / 3;
    int EP = E + N;
    const int* srcp = ei;
    const int* dstp = ei + E;

    char* p = (char*)d_ws;
    auto alloc = [&](size_t bytes) -> char* {
        char* r = p;
        p += (bytes + 255) & ~(size_t)255;
        return r;
    };
    float* style = (float*)alloc(512);
    float* x = (float*)alloc((size_t)N * 128 * 4);
    float* xl = (float*)alloc((size_t)N * 256 * 4);
    float* xr = (float*)alloc((size_t)N * 256 * 4);
    float* y = (float*)alloc((size_t)N * 128 * 4);
    float* stats = (float*)alloc(1024);
    int* rowptr = (int*)alloc(((size_t)N + 1) * 4);
    int* counts = (int*)alloc((size_t)N * 4);
    int* fillc = (int*)alloc((size_t)N * 4);
    int* col = (int*)alloc((size_t)EP * 4);

    // style + node embedding (h1 staged in xl scratch)
    style_k<<<1, 128, 0, stream>>>(zg, W_s1, b_s1, W_s2, b_s2, style);
    ne1_k<<<(N * 128 + 255) / 256, 256, 0, stream>>>(tv, W_ne1, b_ne1, xl, N);
    linear_k<128, false, true><<<(N + 15) / 16, 256, 0, stream>>>(xl, W_ne2, b_ne2, style, x, N);

    // CSR by destination (rebuilt every launch; identical work each call)
    hipMemsetAsync(counts, 0, (size_t)N * 4, stream);
    hipMemsetAsync(fillc, 0, (size_t)N * 4, stream);
    count_k<<<(EP + 255) / 256, 256, 0, stream>>>(dstp, counts, E, EP);
    scan_k<<<1, 1024, 0, stream>>>(counts, rowptr, N, EP);
    fill_k<<<(EP + 255) / 256, 256, 0, stream>>>(srcp, dstp, rowptr, fillc, col, E, EP);

    const int HS[3] = {2, 2, 1};
    for (int L = 0; L < 3; L++) {
        if (HS[L] == 2) {
            linear_k<256, false, false><<<(N + 7) / 8, 256, 0, stream>>>(x, Wl[L], bl[L], nullptr, xl, N);
            linear_k<256, false, false><<<(N + 7) / 8, 256, 0, stream>>>(x, Wr[L], br[L], nullptr, xr, N);
            gat_gather_k<2><<<N, 128, 0, stream>>>(xl, xr, attp[L], bop[L], rowptr, col, y, N);
        } else {
            linear_k<128, false, false><<<(N + 15) / 16, 256, 0, stream>>>(x, Wl[L], bl[L], nullptr, xl, N);
            linear_k<128, false, false><<<(N + 15) / 16, 256, 0, stream>>>(x, Wr[L], br[L], nullptr, xr, N);
            gat_gather_k<1><<<N, 64, 0, stream>>>(xl, xr, attp[L], bop[L], rowptr, col, y, N);
        }
        hipMemsetAsync(stats, 0, 1024, stream);
        gn_stats_k<<<512, 128, 0, stream>>>(y, stats, N);
        gn_apply_k<<<(N * 32 + 255) / 256, 256, 0, stream>>>(y, stats, gnw[L], gnb[L], gnms[L], x, N);
    }

    // head: h = gelu(x@W_h1+b_h1) staged in xl; out = h@W_h2 + b_h2
    linear_k<64, true, false><<<(N + 31) / 32, 256, 0, stream>>>(x, W_h1, b_h1, nullptr, xl, N);
    head2_k<<<(N + 255) / 256, 256, 0, stream>>>(xl, W_h2, b_h2, (float*)d_out, N);
}

// Round 3
// 987.558 us; speedup vs baseline: 1.1150x; 1.1150x over previous
//
#include <hip/hip_runtime.h>
#include <math.h>

#define DEVINL __device__ __forceinline__

using bf16x8 = __attribute__((ext_vector_type(8))) short;
using f32x4  = __attribute__((ext_vector_type(4))) float;

DEVINL float gelu_f(float v) { return 0.5f * v * (1.0f + erff(v * 0.7071067811865475f)); }
DEVINL float lrelu_f(float v) { return v > 0.0f ? v : 0.2f * v; }
DEVINL unsigned short f2bf(float f) {
    union { float f; unsigned u; } c; c.f = f;
    unsigned r = c.u + 0x7fffu + ((c.u >> 16) & 1u);
    return (unsigned short)(r >> 16);
}
DEVINL float bf2f(unsigned short s) {
    union { unsigned u; float f; } c; c.u = (unsigned)s << 16;
    return c.f;
}

// ---------------- style: style = gelu(z_g@W_s1+b_s1)@W_s2 + b_s2 ----------------
__global__ void style_k(const float* __restrict__ zg, const float* __restrict__ W1,
                        const float* __restrict__ b1, const float* __restrict__ W2,
                        const float* __restrict__ b2, float* __restrict__ style) {
    __shared__ float s1[128];
    int j = threadIdx.x;
    float a = b1[j];
    for (int k = 0; k < 256; k++) a = fmaf(zg[k], W1[k * 128 + j], a);
    s1[j] = gelu_f(a);
    __syncthreads();
    float o = b2[j];
    for (int k = 0; k < 128; k++) o = fmaf(s1[k], W2[k * 128 + j], o);
    style[j] = o;
}

// ---------------- node-embed layer 1: h1 = gelu(tv@W_ne1 + b_ne1), f32 out ------
__global__ void ne1_k(const float* __restrict__ tv, const float* __restrict__ W,
                      const float* __restrict__ b, float* __restrict__ h1, int Nn) {
    int idx = blockIdx.x * blockDim.x + threadIdx.x;
    if (idx >= Nn * 128) return;
    int n = idx >> 7, c = idx & 127;
    float o = fmaf(tv[n * 3 + 0], W[c],
              fmaf(tv[n * 3 + 1], W[128 + c],
              fmaf(tv[n * 3 + 2], W[256 + c], b[c])));
    h1[idx] = gelu_f(o);
}

// -------- weight prep: f32 W[128][OUT] -> bf16 hi/lo WT[OUT][128] pairs ----------
struct PrepArgs {
    const float* src[8];
    unsigned short* dsth[8];
    unsigned short* dstl[8];
    int off[9];
    int shift[8];  // log2(OUT)
};
__global__ void prep_k(PrepArgs a) {
    int idx = blockIdx.x * 256 + threadIdx.x;
    if (idx >= a.off[8]) return;
    int s = 0;
    while (idx >= a.off[s + 1]) s++;
    int e = idx - a.off[s];
    int sh = a.shift[s];
    int k = e >> sh, j = e & ((1 << sh) - 1);
    float w = a.src[s][e];
    unsigned short hi = f2bf(w);
    unsigned short lo = f2bf(w - bf2f(hi));
    a.dsth[s][j * 128 + k] = hi;
    a.dstl[s][j * 128 + k] = lo;
}

// ---------------- split-MFMA linear: near-f32 accuracy ---------------------------
// x f32 [Nn][128] split in-kernel to hi/lo bf16; W pre-split. 3 MFMAs per chunk:
// Wh*xh + Wh*xl + Wl*xh  (Wl*xl ~2^-18, dropped).
// D layout (verified m89): n = lane&15 (=row), j = j0 + (lane>>4)*4 + i.
template <int OUT, int EPI, bool DUAL>  // EPI 0:bias 1:bias+style 2:bias+gelu
__global__ __launch_bounds__(256) void mfma_lin_k(
    const float* __restrict__ xin,
    const unsigned short* __restrict__ WH0, const unsigned short* __restrict__ WL0,
    const float* __restrict__ b0,
    const unsigned short* __restrict__ WH1, const unsigned short* __restrict__ WL1,
    const float* __restrict__ b1,
    const float* __restrict__ style,
    float* __restrict__ out0, float* __restrict__ out1, int Nn) {
    int t = threadIdx.x;
    int wave = t >> 6, lane = t & 63;
    int lr = lane & 15, lk = lane >> 4;
    int base = blockIdx.x * 128 + wave * 32;
    int r0 = base + lr, r1 = base + 16 + lr;
    int cr0 = min(r0, Nn - 1), cr1 = min(r1, Nn - 1);

    bf16x8 xh[2][4], xlo[2][4];
#pragma unroll
    for (int rr = 0; rr < 2; rr++) {
        const float* px = xin + (size_t)(rr ? cr1 : cr0) * 128;
#pragma unroll
        for (int s = 0; s < 4; s++) {
            const float4* p4 = (const float4*)(px + s * 32 + lk * 8);
            float4 a = p4[0], b = p4[1];
            float v[8] = {a.x, a.y, a.z, a.w, b.x, b.y, b.z, b.w};
            bf16x8 h, l;
#pragma unroll
            for (int i = 0; i < 8; i++) {
                unsigned short hb = f2bf(v[i]);
                h[i] = (short)hb;
                l[i] = (short)f2bf(v[i] - bf2f(hb));
            }
            xh[rr][s] = h;
            xlo[rr][s] = l;
        }
    }

#pragma unroll
    for (int m = 0; m < (DUAL ? 2 : 1); m++) {
        const unsigned short* WH = (DUAL && m) ? WH1 : WH0;
        const unsigned short* WL = (DUAL && m) ? WL1 : WL0;
        const float* bias = (DUAL && m) ? b1 : b0;
        float* out = (DUAL && m) ? out1 : out0;
        for (int j0 = 0; j0 < OUT; j0 += 16) {
            const bf16x8* pwh = (const bf16x8*)(WH + (size_t)(j0 + lr) * 128);
            const bf16x8* pwl = (const bf16x8*)(WL + (size_t)(j0 + lr) * 128);
            f32x4 acc0 = {0.f, 0.f, 0.f, 0.f}, acc1 = {0.f, 0.f, 0.f, 0.f};
#pragma unroll
            for (int s = 0; s < 4; s++) {
                bf16x8 wh = pwh[s * 4 + lk];
                bf16x8 wl = pwl[s * 4 + lk];
                acc0 = __builtin_amdgcn_mfma_f32_16x16x32_bf16(wh, xh[0][s], acc0, 0, 0, 0);
                acc0 = __builtin_amdgcn_mfma_f32_16x16x32_bf16(wh, xlo[0][s], acc0, 0, 0, 0);
                acc0 = __builtin_amdgcn_mfma_f32_16x16x32_bf16(wl, xh[0][s], acc0, 0, 0, 0);
                acc1 = __builtin_amdgcn_mfma_f32_16x16x32_bf16(wh, xh[1][s], acc1, 0, 0, 0);
                acc1 = __builtin_amdgcn_mfma_f32_16x16x32_bf16(wh, xlo[1][s], acc1, 0, 0, 0);
                acc1 = __builtin_amdgcn_mfma_f32_16x16x32_bf16(wl, xh[1][s], acc1, 0, 0, 0);
            }
            int j = j0 + lk * 4;
            float o0[4], o1[4];
#pragma unroll
            for (int i = 0; i < 4; i++) {
                float bb = bias[j + i];
                if (EPI == 1) bb += style[j + i];
                float v0 = acc0[i] + bb, v1 = acc1[i] + bb;
                if (EPI == 2) { v0 = gelu_f(v0); v1 = gelu_f(v1); }
                o0[i] = v0; o1[i] = v1;
            }
            if (r0 < Nn) { f32x4 v = {o0[0], o0[1], o0[2], o0[3]}; *(f32x4*)(out + (size_t)r0 * OUT + j) = v; }
            if (r1 < Nn) { f32x4 v = {o1[0], o1[1], o1[2], o1[3]}; *(f32x4*)(out + (size_t)r1 * OUT + j) = v; }
        }
    }
}

// ---------------- CSR build (by destination), self-loops appended ----------------
__global__ void count_k(const int* __restrict__ dst, int* __restrict__ counts, int E, int EP) {
    int e = blockIdx.x * blockDim.x + threadIdx.x;
    if (e >= EP) return;
    int d = (e < E) ? dst[e] : (e - E);
    atomicAdd(&counts[d], 1);
}

__global__ void scan_k(const int* __restrict__ counts, int* __restrict__ rowptr, int Nn, int total) {
    __shared__ int part[1024];
    int tid = threadIdx.x;
    int chunk = (Nn + 1023) >> 10;
    int s = tid * chunk, e = min(s + chunk, Nn);
    int loc = 0;
    for (int i = s; i < e; i++) loc += counts[i];
    part[tid] = loc;
    __syncthreads();
    for (int off = 1; off < 1024; off <<= 1) {
        int v = (tid >= off) ? part[tid - off] : 0;
        __syncthreads();
        part[tid] += v;
        __syncthreads();
    }
    int run = part[tid] - loc;  // exclusive
    for (int i = s; i < e; i++) { rowptr[i] = run; run += counts[i]; }
    if (e == Nn) rowptr[Nn] = total;
}

__global__ void fill_k(const int* __restrict__ src, const int* __restrict__ dst,
                       const int* __restrict__ rowptr, int* __restrict__ fillc,
                       int* __restrict__ col, int E, int EP) {
    int e = blockIdx.x * blockDim.x + threadIdx.x;
    if (e >= EP) return;
    int d = (e < E) ? dst[e] : (e - E);
    int s = (e < E) ? src[e] : (e - E);
    int pos = atomicAdd(&fillc[d], 1);
    col[rowptr[d] + pos] = s;
}

// ---------------- GATv2 gather: online softmax per (node, head), f32 -------------
// lane owns channels 2*lane, 2*lane+1 (float2 = 8B coalesced loads).
template <int H>
__global__ __launch_bounds__(256) void gat_gather_k(
    const float* __restrict__ xl, const float* __restrict__ xr,
    const float* __restrict__ att, const float* __restrict__ bo,
    const int* __restrict__ rowptr, const int* __restrict__ col,
    float* __restrict__ y, int Nn) {
    constexpr int NPB = (H == 2) ? 2 : 4;
    int slot = threadIdx.x / (64 * H);
    int n = blockIdx.x * NPB + slot;
    int h = (H == 2) ? ((threadIdx.x >> 6) & 1) : 0;
    int lane = threadIdx.x & 63;
    constexpr int HC = H * 128;
    bool act = n < Nn;
    int nn = act ? n : 0;

    float2 av = *(const float2*)(att + h * 128 + 2 * lane);
    float2 xrv = *(const float2*)(xr + (size_t)nn * HC + h * 128 + 2 * lane);

    float m = -1e30f, den = 0.f, acc0 = 0.f, acc1 = 0.f;
    int beg = act ? rowptr[n] : 0, endp = act ? rowptr[n + 1] : 0;
    for (int k = beg; k < endp; k++) {
        int s = col[k];
        float2 v = *(const float2*)(xl + (size_t)s * HC + h * 128 + 2 * lane);
        float e0 = lrelu_f(v.x + xrv.x);
        float e1 = lrelu_f(v.y + xrv.y);
        float p = fmaf(e0, av.x, e1 * av.y);
#pragma unroll
        for (int off = 32; off > 0; off >>= 1) p += __shfl_xor(p, off, 64);
        float nm = fmaxf(m, p);
        float sc = __expf(m - nm);
        float pe = __expf(p - nm);
        den = fmaf(den, sc, pe);
        acc0 = fmaf(acc0, sc, pe * v.x);
        acc1 = fmaf(acc1, sc, pe * v.y);
        m = nm;
    }
    float inv = 1.0f / (den + 1e-16f);
    acc0 *= inv; acc1 *= inv;

    if constexpr (H == 1) {
        if (act) {
            float2 o = make_float2(acc0 + bo[2 * lane], acc1 + bo[2 * lane + 1]);
            *(float2*)(y + (size_t)n * 128 + 2 * lane) = o;
        }
    } else {
        __shared__ float sh[NPB][2][128];
        *(float2*)&sh[slot][h][2 * lane] = make_float2(acc0, acc1);
        __syncthreads();
        if (h == 0 && act) {
            float o0 = (sh[slot][0][2 * lane] + sh[slot][1][2 * lane]) * 0.5f + bo[2 * lane];
            float o1 = (sh[slot][0][2 * lane + 1] + sh[slot][1][2 * lane + 1]) * 0.5f + bo[2 * lane + 1];
            *(float2*)(y + (size_t)n * 128 + 2 * lane) = make_float2(o0, o1);
        }
    }
}

// ---------------- GraphNorm stats: per-channel sum & sumsq -----------------------
__global__ void gn_stats_k(const float* __restrict__ y, float* __restrict__ stats, int Nn) {
    int c = threadIdx.x;  // 128 threads
    int per = (Nn + gridDim.x - 1) / gridDim.x;
    int n0 = blockIdx.x * per, n1 = min(n0 + per, Nn);
    float s = 0.f, s2 = 0.f;
    for (int n = n0; n < n1; n++) {
        float v = y[(size_t)n * 128 + c];
        s += v;
        s2 = fmaf(v, v, s2);
    }
    atomicAdd(&stats[c], s);
    atomicAdd(&stats[128 + c], s2);
}

// ---------------- GraphNorm apply + GELU, f32 out --------------------------------
__global__ void gn_apply_k(const float* __restrict__ y, const float* __restrict__ stats,
                           const float* __restrict__ w, const float* __restrict__ b,
                           const float* __restrict__ ms, float* __restrict__ xo, int Nn) {
    int i4 = blockIdx.x * blockDim.x + threadIdx.x;
    if (i4 >= Nn * 32) return;
    float4 v = reinterpret_cast<const float4*>(y)[i4];
    int c0 = (i4 & 31) * 4;
    float o[4] = {v.x, v.y, v.z, v.w};
    float invN = 1.0f / (float)Nn;
#pragma unroll
    for (int jj = 0; jj < 4; jj++) {
        int c = c0 + jj;
        float mu = stats[c] * invN;
        float ex2 = stats[128 + c] * invN;
        float msv = ms[c];
        float var = ex2 - 2.f * msv * mu * mu + msv * msv * mu * mu;
        float ov = o[jj] - msv * mu;
        float r = rsqrtf(var + 1e-5f);
        o[jj] = gelu_f(fmaf(w[c], ov * r, b[c]));
    }
    float4 res = make_float4(o[0], o[1], o[2], o[3]);
    reinterpret_cast<float4*>(xo)[i4] = res;
}

// ---------------- final head: out = h@W_h2 + b_h2 (OUT=3) ------------------------
__global__ void head2_k(const float* __restrict__ h, const float* __restrict__ W,
                        const float* __restrict__ b, float* __restrict__ out, int Nn) {
    __shared__ float w[192];
    __shared__ float bb[3];
    int t = threadIdx.x;
    if (t < 192) w[t] = W[t];
    if (t < 3) bb[t] = b[t];
    __syncthreads();
    int n = blockIdx.x * blockDim.x + t;
    if (n >= Nn) return;
    float a0 = bb[0], a1 = bb[1], a2 = bb[2];
    const float4* h4 = reinterpret_cast<const float4*>(h + (size_t)n * 64);
    for (int k4 = 0; k4 < 16; k4++) {
        float4 v = h4[k4];
        int k = k4 * 4;
        a0 = fmaf(v.x, w[(k + 0) * 3 + 0], a0); a1 = fmaf(v.x, w[(k + 0) * 3 + 1], a1); a2 = fmaf(v.x, w[(k + 0) * 3 + 2], a2);
        a0 = fmaf(v.y, w[(k + 1) * 3 + 0], a0); a1 = fmaf(v.y, w[(k + 1) * 3 + 1], a1); a2 = fmaf(v.y, w[(k + 1) * 3 + 2], a2);
        a0 = fmaf(v.z, w[(k + 2) * 3 + 0], a0); a1 = fmaf(v.z, w[(k + 2) * 3 + 1], a1); a2 = fmaf(v.z, w[(k + 2) * 3 + 2], a2);
        a0 = fmaf(v.w, w[(k + 3) * 3 + 0], a0); a1 = fmaf(v.w, w[(k + 3) * 3 + 1], a1); a2 = fmaf(v.w, w[(k + 3) * 3 + 2], a2);
    }
    out[n * 3 + 0] = a0;
    out[n * 3 + 1] = a1;
    out[n * 3 + 2] = a2;
}

extern "C" void kernel_launch(void* const* d_in, const int* in_sizes, int n_in,
                              void* d_out, int out_size, void* d_ws, size_t ws_size,
                              hipStream_t stream) {
    const float* zg = (const float*)d_in[0];
    const int* ei = (const int*)d_in[1];
    const float* tv = (const float*)d_in[2];
    const float* W_ne1 = (const float*)d_in[3];
    const float* b_ne1 = (const float*)d_in[4];
    const float* W_ne2 = (const float*)d_in[5];
    const float* b_ne2 = (const float*)d_in[6];
    const float* W_s1 = (const float*)d_in[7];
    const float* b_s1 = (const float*)d_in[8];
    const float* W_s2 = (const float*)d_in[9];
    const float* b_s2 = (const float*)d_in[10];
    const float *Wl[3], *bl[3], *Wr[3], *br[3], *attp[3], *bop[3], *gnw[3], *gnb[3], *gnms[3];
    for (int L = 0; L < 3; L++) {
        int base = 11 + L * 9;
        Wl[L] = (const float*)d_in[base + 0];
        bl[L] = (const float*)d_in[base + 1];
        Wr[L] = (const float*)d_in[base + 2];
        br[L] = (const float*)d_in[base + 3];
        attp[L] = (const float*)d_in[base + 4];
        bop[L] = (const float*)d_in[base + 5];
        gnw[L] = (const float*)d_in[base + 6];
        gnb[L] = (const float*)d_in[base + 7];
        gnms[L] = (const float*)d_in[base + 8];
    }
    const float* W_h1 = (const float*)d_in[38];
    const float* b_h1 = (const float*)d_in[39];
    const float* W_h2 = (const float*)d_in[40];
    const float* b_h2 = (const float*)d_in[41];

    int E = in_sizes[1] / 2;
    int N = in_sizes[2] / 3;
    int EP = E + N;
    const int* srcp = ei;
    const int* dstp = ei + E;

    char* p = (char*)d_ws;
    auto alloc = [&](size_t bytes) -> char* {
        char* r = p;
        p += (bytes + 255) & ~(size_t)255;
        return r;
    };
    float* style = (float*)alloc(512);
    float* h1 = (float*)alloc((size_t)N * 128 * 4);
    float* x = (float*)alloc((size_t)N * 128 * 4);
    float* xle = (float*)alloc((size_t)N * 256 * 4);
    float* xre = (float*)alloc((size_t)N * 256 * 4);
    float* y = (float*)alloc((size_t)N * 128 * 4);
    float* hb = (float*)alloc((size_t)N * 64 * 4);
    float* stats = (float*)alloc(1024);
    int* rowptr = (int*)alloc(((size_t)N + 1) * 4);
    int* counts = (int*)alloc((size_t)N * 4);
    int* fillc = (int*)alloc((size_t)N * 4);
    int* col = (int*)alloc((size_t)EP * 4);
    unsigned short* wth = (unsigned short*)alloc((size_t)188416 * 2);
    unsigned short* wtl = (unsigned short*)alloc((size_t)188416 * 2);

    // weight prep: 8 segments, K=128 all, hi/lo pairs
    PrepArgs pa;
    const float* srcs[8] = {W_ne2, Wl[0], Wr[0], Wl[1], Wr[1], Wl[2], Wr[2], W_h1};
    int outs[8] = {128, 256, 256, 256, 256, 128, 128, 64};
    int off = 0;
    for (int s = 0; s < 8; s++) {
        pa.src[s] = srcs[s];
        pa.dsth[s] = wth + off;
        pa.dstl[s] = wtl + off;
        pa.off[s] = off;
        pa.shift[s] = (outs[s] == 256) ? 8 : (outs[s] == 128 ? 7 : 6);
        off += 128 * outs[s];
    }
    pa.off[8] = off;
    unsigned short *wh_ne2 = pa.dsth[0], *wl_ne2 = pa.dstl[0];
    unsigned short *wh_l[3] = {pa.dsth[1], pa.dsth[3], pa.dsth[5]};
    unsigned short *wl_l[3] = {pa.dstl[1], pa.dstl[3], pa.dstl[5]};
    unsigned short *wh_r[3] = {pa.dsth[2], pa.dsth[4], pa.dsth[6]};
    unsigned short *wl_r[3] = {pa.dstl[2], pa.dstl[4], pa.dstl[6]};
    unsigned short *wh_h1 = pa.dsth[7], *wl_h1 = pa.dstl[7];
    prep_k<<<(off + 255) / 256, 256, 0, stream>>>(pa);

    // style + node embedding
    style_k<<<1, 128, 0, stream>>>(zg, W_s1, b_s1, W_s2, b_s2, style);
    ne1_k<<<(N * 128 + 255) / 256, 256, 0, stream>>>(tv, W_ne1, b_ne1, h1, N);
    mfma_lin_k<128, 1, false><<<(N + 127) / 128, 256, 0, stream>>>(
        h1, wh_ne2, wl_ne2, b_ne2, nullptr, nullptr, nullptr, style, x, nullptr, N);

    // CSR by destination (rebuilt every launch)
    hipMemsetAsync(counts, 0, (size_t)N * 4, stream);
    hipMemsetAsync(fillc, 0, (size_t)N * 4, stream);
    count_k<<<(EP + 255) / 256, 256, 0, stream>>>(dstp, counts, E, EP);
    scan_k<<<1, 1024, 0, stream>>>(counts, rowptr, N, EP);
    fill_k<<<(EP + 255) / 256, 256, 0, stream>>>(srcp, dstp, rowptr, fillc, col, E, EP);

    const int HS[3] = {2, 2, 1};
    for (int L = 0; L < 3; L++) {
        if (HS[L] == 2) {
            mfma_lin_k<256, 0, true><<<(N + 127) / 128, 256, 0, stream>>>(
                x, wh_l[L], wl_l[L], bl[L], wh_r[L], wl_r[L], br[L], nullptr, xle, xre, N);
            gat_gather_k<2><<<(N + 1) / 2, 256, 0, stream>>>(xle, xre, attp[L], bop[L], rowptr, col, y, N);
        } else {
            mfma_lin_k<128, 0, true><<<(N + 127) / 128, 256, 0, stream>>>(
                x, wh_l[L], wl_l[L], bl[L], wh_r[L], wl_r[L], br[L], nullptr, xle, xre, N);
            gat_gather_k<1><<<(N + 3) / 4, 256, 0, stream>>>(xle, xre, attp[L], bop[L], rowptr, col, y, N);
        }
        hipMemsetAsync(stats, 0, 1024, stream);
        gn_stats_k<<<512, 128, 0, stream>>>(y, stats, N);
        gn_apply_k<<<(N * 32 + 255) / 256, 256, 0, stream>>>(y, stats, gnw[L], gnb[L], gnms[L], x, N);
    }

    // head: h = gelu(x@W_h1+b_h1) (split-MFMA, f32 out); out = h@W_h2 + b_h2
    mfma_lin_k<64, 2, false><<<(N + 127) / 128, 256, 0, stream>>>(
        x, wh_h1, wl_h1, b_h1, nullptr, nullptr, nullptr, nullptr, hb, nullptr, N);
    head2_k<<<(N + 255) / 256, 256, 0, stream>>>(hb, W_h2, b_h2, (float*)d_out, N);
}

// Round 4
// 873.854 us; speedup vs baseline: 1.2600x; 1.1301x over previous
//
#include <hip/hip_runtime.h>
#include <math.h>

#define DEVINL __device__ __forceinline__

using bf16x8 = __attribute__((ext_vector_type(8))) short;
using f32x4  = __attribute__((ext_vector_type(4))) float;

DEVINL float gelu_f(float v) { return 0.5f * v * (1.0f + erff(v * 0.7071067811865475f)); }
DEVINL float lrelu_f(float v) { return v > 0.0f ? v : 0.2f * v; }
DEVINL unsigned short f2bf(float f) {
    union { float f; unsigned u; } c; c.f = f;
    unsigned r = c.u + 0x7fffu + ((c.u >> 16) & 1u);
    return (unsigned short)(r >> 16);
}
DEVINL float bf2f(unsigned short s) {
    union { unsigned u; float f; } c; c.u = (unsigned)s << 16;
    return c.f;
}

// ---------------- style: style = gelu(z_g@W_s1+b_s1)@W_s2 + b_s2 ----------------
__global__ void style_k(const float* __restrict__ zg, const float* __restrict__ W1,
                        const float* __restrict__ b1, const float* __restrict__ W2,
                        const float* __restrict__ b2, float* __restrict__ style) {
    __shared__ float s1[128];
    int j = threadIdx.x;
    float a = b1[j];
    for (int k = 0; k < 256; k++) a = fmaf(zg[k], W1[k * 128 + j], a);
    s1[j] = gelu_f(a);
    __syncthreads();
    float o = b2[j];
    for (int k = 0; k < 128; k++) o = fmaf(s1[k], W2[k * 128 + j], o);
    style[j] = o;
}

// ---------------- node-embed layer 1: h1 = gelu(tv@W_ne1 + b_ne1), f32 out ------
__global__ void ne1_k(const float* __restrict__ tv, const float* __restrict__ W,
                      const float* __restrict__ b, float* __restrict__ h1, int Nn) {
    int idx = blockIdx.x * blockDim.x + threadIdx.x;
    if (idx >= Nn * 128) return;
    int n = idx >> 7, c = idx & 127;
    float o = fmaf(tv[n * 3 + 0], W[c],
              fmaf(tv[n * 3 + 1], W[128 + c],
              fmaf(tv[n * 3 + 2], W[256 + c], b[c])));
    h1[idx] = gelu_f(o);
}

// -------- weight prep: f32 W[128][OUT] -> bf16 hi/lo WT[OUT][128] pairs ----------
struct PrepArgs {
    const float* src[8];
    unsigned short* dsth[8];
    unsigned short* dstl[8];
    int off[9];
    int shift[8];  // log2(OUT)
};
__global__ void prep_k(PrepArgs a) {
    int idx = blockIdx.x * 256 + threadIdx.x;
    if (idx >= a.off[8]) return;
    int s = 0;
    while (idx >= a.off[s + 1]) s++;
    int e = idx - a.off[s];
    int sh = a.shift[s];
    int k = e >> sh, j = e & ((1 << sh) - 1);
    float w = a.src[s][e];
    unsigned short hi = f2bf(w);
    unsigned short lo = f2bf(w - bf2f(hi));
    a.dsth[s][j * 128 + k] = hi;
    a.dstl[s][j * 128 + k] = lo;
}

// ---------------- split-MFMA linear: near-f32 accuracy ---------------------------
// x f32 [Nn][128] split in-kernel to hi/lo bf16; W pre-split. 3 MFMAs per chunk:
// Wh*xh + Wh*xl + Wl*xh  (Wl*xl ~2^-18, dropped).
template <int OUT, int EPI, bool DUAL>  // EPI 0:bias 1:bias+style 2:bias+gelu
__global__ __launch_bounds__(256) void mfma_lin_k(
    const float* __restrict__ xin,
    const unsigned short* __restrict__ WH0, const unsigned short* __restrict__ WL0,
    const float* __restrict__ b0,
    const unsigned short* __restrict__ WH1, const unsigned short* __restrict__ WL1,
    const float* __restrict__ b1,
    const float* __restrict__ style,
    float* __restrict__ out0, float* __restrict__ out1, int Nn) {
    int t = threadIdx.x;
    int wave = t >> 6, lane = t & 63;
    int lr = lane & 15, lk = lane >> 4;
    int base = blockIdx.x * 128 + wave * 32;
    int r0 = base + lr, r1 = base + 16 + lr;
    int cr0 = min(r0, Nn - 1), cr1 = min(r1, Nn - 1);

    bf16x8 xh[2][4], xlo[2][4];
#pragma unroll
    for (int rr = 0; rr < 2; rr++) {
        const float* px = xin + (size_t)(rr ? cr1 : cr0) * 128;
#pragma unroll
        for (int s = 0; s < 4; s++) {
            const float4* p4 = (const float4*)(px + s * 32 + lk * 8);
            float4 a = p4[0], b = p4[1];
            float v[8] = {a.x, a.y, a.z, a.w, b.x, b.y, b.z, b.w};
            bf16x8 h, l;
#pragma unroll
            for (int i = 0; i < 8; i++) {
                unsigned short hb = f2bf(v[i]);
                h[i] = (short)hb;
                l[i] = (short)f2bf(v[i] - bf2f(hb));
            }
            xh[rr][s] = h;
            xlo[rr][s] = l;
        }
    }

#pragma unroll
    for (int m = 0; m < (DUAL ? 2 : 1); m++) {
        const unsigned short* WH = (DUAL && m) ? WH1 : WH0;
        const unsigned short* WL = (DUAL && m) ? WL1 : WL0;
        const float* bias = (DUAL && m) ? b1 : b0;
        float* out = (DUAL && m) ? out1 : out0;
        for (int j0 = 0; j0 < OUT; j0 += 16) {
            const bf16x8* pwh = (const bf16x8*)(WH + (size_t)(j0 + lr) * 128);
            const bf16x8* pwl = (const bf16x8*)(WL + (size_t)(j0 + lr) * 128);
            f32x4 acc0 = {0.f, 0.f, 0.f, 0.f}, acc1 = {0.f, 0.f, 0.f, 0.f};
#pragma unroll
            for (int s = 0; s < 4; s++) {
                bf16x8 wh = pwh[s * 4 + lk];
                bf16x8 wl = pwl[s * 4 + lk];
                acc0 = __builtin_amdgcn_mfma_f32_16x16x32_bf16(wh, xh[0][s], acc0, 0, 0, 0);
                acc0 = __builtin_amdgcn_mfma_f32_16x16x32_bf16(wh, xlo[0][s], acc0, 0, 0, 0);
                acc0 = __builtin_amdgcn_mfma_f32_16x16x32_bf16(wl, xh[0][s], acc0, 0, 0, 0);
                acc1 = __builtin_amdgcn_mfma_f32_16x16x32_bf16(wh, xh[1][s], acc1, 0, 0, 0);
                acc1 = __builtin_amdgcn_mfma_f32_16x16x32_bf16(wh, xlo[1][s], acc1, 0, 0, 0);
                acc1 = __builtin_amdgcn_mfma_f32_16x16x32_bf16(wl, xh[1][s], acc1, 0, 0, 0);
            }
            int j = j0 + lk * 4;
            float o0[4], o1[4];
#pragma unroll
            for (int i = 0; i < 4; i++) {
                float bb = bias[j + i];
                if (EPI == 1) bb += style[j + i];
                float v0 = acc0[i] + bb, v1 = acc1[i] + bb;
                if (EPI == 2) { v0 = gelu_f(v0); v1 = gelu_f(v1); }
                o0[i] = v0; o1[i] = v1;
            }
            if (r0 < Nn) { f32x4 v = {o0[0], o0[1], o0[2], o0[3]}; *(f32x4*)(out + (size_t)r0 * OUT + j) = v; }
            if (r1 < Nn) { f32x4 v = {o1[0], o1[1], o1[2], o1[3]}; *(f32x4*)(out + (size_t)r1 * OUT + j) = v; }
        }
    }
}

// ---------------- CSR build (by destination), self-loops appended ----------------
__global__ void count_k(const int* __restrict__ dst, int* __restrict__ counts, int E, int EP) {
    int e = blockIdx.x * blockDim.x + threadIdx.x;
    if (e >= EP) return;
    int d = (e < E) ? dst[e] : (e - E);
    atomicAdd(&counts[d], 1);
}

__global__ void scan_k(const int* __restrict__ counts, int* __restrict__ rowptr, int Nn, int total) {
    __shared__ int part[1024];
    int tid = threadIdx.x;
    int chunk = (Nn + 1023) >> 10;
    int s = tid * chunk, e = min(s + chunk, Nn);
    int loc = 0;
    for (int i = s; i < e; i++) loc += counts[i];
    part[tid] = loc;
    __syncthreads();
    for (int off = 1; off < 1024; off <<= 1) {
        int v = (tid >= off) ? part[tid - off] : 0;
        __syncthreads();
        part[tid] += v;
        __syncthreads();
    }
    int run = part[tid] - loc;  // exclusive
    for (int i = s; i < e; i++) { rowptr[i] = run; run += counts[i]; }
    if (e == Nn) rowptr[Nn] = total;
}

__global__ void fill_k(const int* __restrict__ src, const int* __restrict__ dst,
                       const int* __restrict__ rowptr, int* __restrict__ fillc,
                       int* __restrict__ col, int E, int EP) {
    int e = blockIdx.x * blockDim.x + threadIdx.x;
    if (e >= EP) return;
    int d = (e < E) ? dst[e] : (e - E);
    int s = (e < E) ? src[e] : (e - E);
    int pos = atomicAdd(&fillc[d], 1);
    col[rowptr[d] + pos] = s;
}

// ---------------- GATv2 gather: 4 edges/iter, 16 lanes x 8ch each ----------------
// No running max (logits bounded O(3): softmax shift-invariant, exp safe).
// group g = lane>>4 handles edge k0+g; lane sub&15 owns channels sub*8..sub*8+7.
template <int H>
__global__ __launch_bounds__(256) void gat_gather_k(
    const float* __restrict__ xl, const float* __restrict__ xr,
    const float* __restrict__ att, const float* __restrict__ bo,
    const int* __restrict__ rowptr, const int* __restrict__ col,
    float* __restrict__ y, int Nn) {
    constexpr int NPB = (H == 2) ? 2 : 4;   // nodes per block (4 waves)
    int w = threadIdx.x >> 6;
    int slot = (H == 2) ? (w >> 1) : w;
    int h = (H == 2) ? (w & 1) : 0;
    int lane = threadIdx.x & 63;
    int g = lane >> 4, sub = lane & 15;
    constexpr int HC = H * 128;
    int n = blockIdx.x * NPB + slot;
    bool act = n < Nn;
    int nn = act ? n : 0;

    const float* xrp = xr + (size_t)nn * HC + h * 128 + sub * 8;
    float4 xr0 = *(const float4*)xrp, xr1 = *(const float4*)(xrp + 4);
    const float* ap = att + h * 128 + sub * 8;
    float4 a0 = *(const float4*)ap, a1 = *(const float4*)(ap + 4);

    float den = 0.f;
    float acc[8] = {0.f, 0.f, 0.f, 0.f, 0.f, 0.f, 0.f, 0.f};
    int beg = act ? rowptr[n] : 0, endp = act ? rowptr[n + 1] : 0;

    for (int k0 = beg; k0 < endp; k0 += 4) {
        int k = k0 + g;
        bool ev = k < endp;
        int s = col[ev ? k : beg];
        const float* vp = xl + (size_t)s * HC + h * 128 + sub * 8;
        float4 v0 = *(const float4*)vp, v1 = *(const float4*)(vp + 4);
        float p;
        p = lrelu_f(v0.x + xr0.x) * a0.x;
        p = fmaf(lrelu_f(v0.y + xr0.y), a0.y, p);
        p = fmaf(lrelu_f(v0.z + xr0.z), a0.z, p);
        p = fmaf(lrelu_f(v0.w + xr0.w), a0.w, p);
        p = fmaf(lrelu_f(v1.x + xr1.x), a1.x, p);
        p = fmaf(lrelu_f(v1.y + xr1.y), a1.y, p);
        p = fmaf(lrelu_f(v1.z + xr1.z), a1.z, p);
        p = fmaf(lrelu_f(v1.w + xr1.w), a1.w, p);
        // reduce across the 16-lane group (xor of bits 0..3 stays in-group)
        p += __shfl_xor(p, 1, 64);
        p += __shfl_xor(p, 2, 64);
        p += __shfl_xor(p, 4, 64);
        p += __shfl_xor(p, 8, 64);
        float pe = ev ? __expf(p) : 0.f;
        den += pe;
        acc[0] = fmaf(pe, v0.x, acc[0]);
        acc[1] = fmaf(pe, v0.y, acc[1]);
        acc[2] = fmaf(pe, v0.z, acc[2]);
        acc[3] = fmaf(pe, v0.w, acc[3]);
        acc[4] = fmaf(pe, v1.x, acc[4]);
        acc[5] = fmaf(pe, v1.y, acc[5]);
        acc[6] = fmaf(pe, v1.z, acc[6]);
        acc[7] = fmaf(pe, v1.w, acc[7]);
    }
    // cross-group combine (once per node)
#pragma unroll
    for (int off = 16; off <= 32; off <<= 1) {
        den += __shfl_xor(den, off, 64);
#pragma unroll
        for (int j = 0; j < 8; j++) acc[j] += __shfl_xor(acc[j], off, 64);
    }
    float inv = 1.0f / (den + 1e-16f);

    if constexpr (H == 1) {
        if (act && g == 0) {
            const float* bp = bo + sub * 8;
            f32x4 o0 = {acc[0] * inv + bp[0], acc[1] * inv + bp[1], acc[2] * inv + bp[2], acc[3] * inv + bp[3]};
            f32x4 o1 = {acc[4] * inv + bp[4], acc[5] * inv + bp[5], acc[6] * inv + bp[6], acc[7] * inv + bp[7]};
            *(f32x4*)(y + (size_t)n * 128 + sub * 8) = o0;
            *(f32x4*)(y + (size_t)n * 128 + sub * 8 + 4) = o1;
        }
    } else {
        __shared__ float sh[NPB][2][128];
        if (g == 0) {
#pragma unroll
            for (int j = 0; j < 8; j++) sh[slot][h][sub * 8 + j] = acc[j] * inv;
        }
        __syncthreads();
        int t = threadIdx.x;
        int slot2 = t >> 7, c = t & 127;
        int n2 = blockIdx.x * NPB + slot2;
        if (n2 < Nn)
            y[(size_t)n2 * 128 + c] = (sh[slot2][0][c] + sh[slot2][1][c]) * 0.5f + bo[c];
    }
}

// ---------------- GraphNorm stats: per-channel sum & sumsq -----------------------
__global__ void gn_stats_k(const float* __restrict__ y, float* __restrict__ stats, int Nn) {
    int c = threadIdx.x;  // 128 threads
    int per = (Nn + gridDim.x - 1) / gridDim.x;
    int n0 = blockIdx.x * per, n1 = min(n0 + per, Nn);
    float s = 0.f, s2 = 0.f;
    for (int n = n0; n < n1; n++) {
        float v = y[(size_t)n * 128 + c];
        s += v;
        s2 = fmaf(v, v, s2);
    }
    atomicAdd(&stats[c], s);
    atomicAdd(&stats[128 + c], s2);
}

// ---------------- GraphNorm apply + GELU, f32 out --------------------------------
__global__ void gn_apply_k(const float* __restrict__ y, const float* __restrict__ stats,
                           const float* __restrict__ w, const float* __restrict__ b,
                           const float* __restrict__ ms, float* __restrict__ xo, int Nn) {
    int i4 = blockIdx.x * blockDim.x + threadIdx.x;
    if (i4 >= Nn * 32) return;
    float4 v = reinterpret_cast<const float4*>(y)[i4];
    int c0 = (i4 & 31) * 4;
    float o[4] = {v.x, v.y, v.z, v.w};
    float invN = 1.0f / (float)Nn;
#pragma unroll
    for (int jj = 0; jj < 4; jj++) {
        int c = c0 + jj;
        float mu = stats[c] * invN;
        float ex2 = stats[128 + c] * invN;
        float msv = ms[c];
        float var = ex2 - 2.f * msv * mu * mu + msv * msv * mu * mu;
        float ov = o[jj] - msv * mu;
        float r = rsqrtf(var + 1e-5f);
        o[jj] = gelu_f(fmaf(w[c], ov * r, b[c]));
    }
    float4 res = make_float4(o[0], o[1], o[2], o[3]);
    reinterpret_cast<float4*>(xo)[i4] = res;
}

// ---------------- final head: out = h@W_h2 + b_h2 (OUT=3) ------------------------
__global__ void head2_k(const float* __restrict__ h, const float* __restrict__ W,
                        const float* __restrict__ b, float* __restrict__ out, int Nn) {
    __shared__ float w[192];
    __shared__ float bb[3];
    int t = threadIdx.x;
    if (t < 192) w[t] = W[t];
    if (t < 3) bb[t] = b[t];
    __syncthreads();
    int n = blockIdx.x * blockDim.x + t;
    if (n >= Nn) return;
    float a0 = bb[0], a1 = bb[1], a2 = bb[2];
    const float4* h4 = reinterpret_cast<const float4*>(h + (size_t)n * 64);
    for (int k4 = 0; k4 < 16; k4++) {
        float4 v = h4[k4];
        int k = k4 * 4;
        a0 = fmaf(v.x, w[(k + 0) * 3 + 0], a0); a1 = fmaf(v.x, w[(k + 0) * 3 + 1], a1); a2 = fmaf(v.x, w[(k + 0) * 3 + 2], a2);
        a0 = fmaf(v.y, w[(k + 1) * 3 + 0], a0); a1 = fmaf(v.y, w[(k + 1) * 3 + 1], a1); a2 = fmaf(v.y, w[(k + 1) * 3 + 2], a2);
        a0 = fmaf(v.z, w[(k + 2) * 3 + 0], a0); a1 = fmaf(v.z, w[(k + 2) * 3 + 1], a1); a2 = fmaf(v.z, w[(k + 2) * 3 + 2], a2);
        a0 = fmaf(v.w, w[(k + 3) * 3 + 0], a0); a1 = fmaf(v.w, w[(k + 3) * 3 + 1], a1); a2 = fmaf(v.w, w[(k + 3) * 3 + 2], a2);
    }
    out[n * 3 + 0] = a0;
    out[n * 3 + 1] = a1;
    out[n * 3 + 2] = a2;
}

extern "C" void kernel_launch(void* const* d_in, const int* in_sizes, int n_in,
                              void* d_out, int out_size, void* d_ws, size_t ws_size,
                              hipStream_t stream) {
    const float* zg = (const float*)d_in[0];
    const int* ei = (const int*)d_in[1];
    const float* tv = (const float*)d_in[2];
    const float* W_ne1 = (const float*)d_in[3];
    const float* b_ne1 = (const float*)d_in[4];
    const float* W_ne2 = (const float*)d_in[5];
    const float* b_ne2 = (const float*)d_in[6];
    const float* W_s1 = (const float*)d_in[7];
    const float* b_s1 = (const float*)d_in[8];
    const float* W_s2 = (const float*)d_in[9];
    const float* b_s2 = (const float*)d_in[10];
    const float *Wl[3], *bl[3], *Wr[3], *br[3], *attp[3], *bop[3], *gnw[3], *gnb[3], *gnms[3];
    for (int L = 0; L < 3; L++) {
        int base = 11 + L * 9;
        Wl[L] = (const float*)d_in[base + 0];
        bl[L] = (const float*)d_in[base + 1];
        Wr[L] = (const float*)d_in[base + 2];
        br[L] = (const float*)d_in[base + 3];
        attp[L] = (const float*)d_in[base + 4];
        bop[L] = (const float*)d_in[base + 5];
        gnw[L] = (const float*)d_in[base + 6];
        gnb[L] = (const float*)d_in[base + 7];
        gnms[L] = (const float*)d_in[base + 8];
    }
    const float* W_h1 = (const float*)d_in[38];
    const float* b_h1 = (const float*)d_in[39];
    const float* W_h2 = (const float*)d_in[40];
    const float* b_h2 = (const float*)d_in[41];

    int E = in_sizes[1] / 2;
    int N = in_sizes[2] / 3;
    int EP = E + N;
    const int* srcp = ei;
    const int* dstp = ei + E;

    char* p = (char*)d_ws;
    auto alloc = [&](size_t bytes) -> char* {
        char* r = p;
        p += (bytes + 255) & ~(size_t)255;
        return r;
    };
    float* style = (float*)alloc(512);
    float* h1 = (float*)alloc((size_t)N * 128 * 4);
    float* x = (float*)alloc((size_t)N * 128 * 4);
    float* xle = (float*)alloc((size_t)N * 256 * 4);
    float* xre = (float*)alloc((size_t)N * 256 * 4);
    float* y = (float*)alloc((size_t)N * 128 * 4);
    float* hb = (float*)alloc((size_t)N * 64 * 4);
    float* stats = (float*)alloc(1024);
    int* rowptr = (int*)alloc(((size_t)N + 1) * 4);
    int* counts = (int*)alloc((size_t)N * 4);
    int* fillc = (int*)alloc((size_t)N * 4);
    int* col = (int*)alloc((size_t)EP * 4);
    unsigned short* wth = (unsigned short*)alloc((size_t)188416 * 2);
    unsigned short* wtl = (unsigned short*)alloc((size_t)188416 * 2);

    // weight prep: 8 segments, K=128 all, hi/lo pairs
    PrepArgs pa;
    const float* srcs[8] = {W_ne2, Wl[0], Wr[0], Wl[1], Wr[1], Wl[2], Wr[2], W_h1};
    int outs[8] = {128, 256, 256, 256, 256, 128, 128, 64};
    int off = 0;
    for (int s = 0; s < 8; s++) {
        pa.src[s] = srcs[s];
        pa.dsth[s] = wth + off;
        pa.dstl[s] = wtl + off;
        pa.off[s] = off;
        pa.shift[s] = (outs[s] == 256) ? 8 : (outs[s] == 128 ? 7 : 6);
        off += 128 * outs[s];
    }
    pa.off[8] = off;
    unsigned short *wh_ne2 = pa.dsth[0], *wl_ne2 = pa.dstl[0];
    unsigned short *wh_l[3] = {pa.dsth[1], pa.dsth[3], pa.dsth[5]};
    unsigned short *wl_l[3] = {pa.dstl[1], pa.dstl[3], pa.dstl[5]};
    unsigned short *wh_r[3] = {pa.dsth[2], pa.dsth[4], pa.dsth[6]};
    unsigned short *wl_r[3] = {pa.dstl[2], pa.dstl[4], pa.dstl[6]};
    unsigned short *wh_h1 = pa.dsth[7], *wl_h1 = pa.dstl[7];
    prep_k<<<(off + 255) / 256, 256, 0, stream>>>(pa);

    // style + node embedding
    style_k<<<1, 128, 0, stream>>>(zg, W_s1, b_s1, W_s2, b_s2, style);
    ne1_k<<<(N * 128 + 255) / 256, 256, 0, stream>>>(tv, W_ne1, b_ne1, h1, N);
    mfma_lin_k<128, 1, false><<<(N + 127) / 128, 256, 0, stream>>>(
        h1, wh_ne2, wl_ne2, b_ne2, nullptr, nullptr, nullptr, style, x, nullptr, N);

    // CSR by destination (rebuilt every launch)
    hipMemsetAsync(counts, 0, (size_t)N * 4, stream);
    hipMemsetAsync(fillc, 0, (size_t)N * 4, stream);
    count_k<<<(EP + 255) / 256, 256, 0, stream>>>(dstp, counts, E, EP);
    scan_k<<<1, 1024, 0, stream>>>(counts, rowptr, N, EP);
    fill_k<<<(EP + 255) / 256, 256, 0, stream>>>(srcp, dstp, rowptr, fillc, col, E, EP);

    const int HS[3] = {2, 2, 1};
    for (int L = 0; L < 3; L++) {
        if (HS[L] == 2) {
            mfma_lin_k<256, 0, true><<<(N + 127) / 128, 256, 0, stream>>>(
                x, wh_l[L], wl_l[L], bl[L], wh_r[L], wl_r[L], br[L], nullptr, xle, xre, N);
            gat_gather_k<2><<<(N + 1) / 2, 256, 0, stream>>>(xle, xre, attp[L], bop[L], rowptr, col, y, N);
        } else {
            mfma_lin_k<128, 0, true><<<(N + 127) / 128, 256, 0, stream>>>(
                x, wh_l[L], wl_l[L], bl[L], wh_r[L], wl_r[L], br[L], nullptr, xle, xre, N);
            gat_gather_k<1><<<(N + 3) / 4, 256, 0, stream>>>(xle, xre, attp[L], bop[L], rowptr, col, y, N);
        }
        hipMemsetAsync(stats, 0, 1024, stream);
        gn_stats_k<<<512, 128, 0, stream>>>(y, stats, N);
        gn_apply_k<<<(N * 32 + 255) / 256, 256, 0, stream>>>(y, stats, gnw[L], gnb[L], gnms[L], x, N);
    }

    // head: h = gelu(x@W_h1+b_h1) (split-MFMA, f32 out); out = h@W_h2 + b_h2
    mfma_lin_k<64, 2, false><<<(N + 127) / 128, 256, 0, stream>>>(
        x, wh_h1, wl_h1, b_h1, nullptr, nullptr, nullptr, nullptr, hb, nullptr, N);
    head2_k<<<(N + 255) / 256, 256, 0, stream>>>(hb, W_h2, b_h2, (float*)d_out, N);
}